// Round 3
// baseline (242.723 us; speedup 1.0000x reference)
//
#include <hip/hip_runtime.h>

#define Dn 20000
#define Bn 32

// ws layout (floats):
//   F1  : [20000][128] at 0
//   FjT : [128][20000] at 2,560,000
//   c   : [32][16]     at 5,120,000
//   base: [32][128]    at 5,120,512
// total ~20.5 MB

// ---------------- A1: F1[d][k] = b1[k] + f_bias[d]*W1[17][k] + sum_i F_embed[d][i]*W1[1+i][k]
__global__ __launch_bounds__(256) void kA1(const float* __restrict__ F_embed,
                                           const float* __restrict__ f_bias,
                                           const float* __restrict__ W1,
                                           const float* __restrict__ b1,
                                           float* __restrict__ F1)
{
    const int t  = threadIdx.x;
    const int k  = t & 127;
    const int dl = t >> 7;
    const int d0 = blockIdx.x * 8;
    float w[17];
#pragma unroll
    for (int i = 0; i < 16; ++i) w[i] = W1[(1 + i) * 128 + k];
    w[16] = W1[17 * 128 + k];
    const float bb = b1[k];
#pragma unroll
    for (int r = 0; r < 4; ++r) {
        const int d = d0 + r * 2 + dl;   // grid exact: 2500*8 = 20000
        float acc = fmaf(f_bias[d], w[16], bb);
#pragma unroll
        for (int i = 0; i < 16; ++i) acc = fmaf(F_embed[d * 16 + i], w[i], acc);
        F1[d * 128 + k] = acc;
    }
}

// ---------------- A2: FjT[k][d] = f_bias[d]*Wj1[144][k] + sum_i F_embed[d][i]*Wj1[128+i][k]
__global__ __launch_bounds__(256) void kA2(const float* __restrict__ F_embed,
                                           const float* __restrict__ f_bias,
                                           const float* __restrict__ Wj1,
                                           float* __restrict__ FjT)
{
    const int d  = blockIdx.x * 256 + threadIdx.x;
    const int kg = blockIdx.y * 8;
    if (d >= Dn) return;
    const float4* fe4 = (const float4*)(F_embed + d * 16);
    float fe[16];
    {
        float4 a = fe4[0], b = fe4[1], c = fe4[2], e = fe4[3];
        fe[0]=a.x; fe[1]=a.y; fe[2]=a.z; fe[3]=a.w;
        fe[4]=b.x; fe[5]=b.y; fe[6]=b.z; fe[7]=b.w;
        fe[8]=c.x; fe[9]=c.y; fe[10]=c.z; fe[11]=c.w;
        fe[12]=e.x; fe[13]=e.y; fe[14]=e.z; fe[15]=e.w;
    }
    const float fb = f_bias[d];
#pragma unroll
    for (int j = 0; j < 8; ++j) {
        const int k = kg + j;
        float acc = fb * Wj1[144 * 128 + k];
#pragma unroll
        for (int i = 0; i < 16; ++i) acc = fmaf(fe[i], Wj1[(128 + i) * 128 + k], acc);
        FjT[k * Dn + d] = acc;
    }
}

// ---------------- B: fused stage1+2 + masked reduce into c[32][16]
// lane b = t&31 (F1 reads broadcast), 8 d-slots per block-iteration, 5 iterations.
#define NDB 40
__global__ __launch_bounds__(256) void kB(const float* __restrict__ x,
                                          const int* __restrict__ mask,
                                          const float* __restrict__ F1,
                                          const float* __restrict__ W1,  // row 0 used
                                          const float* __restrict__ W2,
                                          const float* __restrict__ b2,
                                          float* __restrict__ cws)
{
    const int t   = threadIdx.x;
    const int b   = t & 31;
    const int dsl = t >> 5;
    const int d0  = blockIdx.x * NDB;
    float cacc[16];
#pragma unroll
    for (int j = 0; j < 16; ++j) cacc[j] = 0.f;

    for (int it = 0; it < 5; ++it) {
        const int d = d0 + it * 8 + dsl;   // 500*40 = 20000 exact
        const float xv = x[b * Dn + d];
        const float m  = (float)mask[b * Dn + d];
        float acc[16];
#pragma unroll
        for (int j = 0; j < 16; ++j) acc[j] = 0.f;
        const float4* f14 = (const float4*)(F1 + d * 128);
#pragma unroll 8
        for (int k4 = 0; k4 < 32; ++k4) {
            const float4 f = f14[k4];
            const float h0 = fmaxf(fmaf(xv, W1[k4 * 4 + 0], f.x), 0.f);
            const float h1 = fmaxf(fmaf(xv, W1[k4 * 4 + 1], f.y), 0.f);
            const float h2 = fmaxf(fmaf(xv, W1[k4 * 4 + 2], f.z), 0.f);
            const float h3 = fmaxf(fmaf(xv, W1[k4 * 4 + 3], f.w), 0.f);
#pragma unroll
            for (int j = 0; j < 16; ++j) {
                float a = acc[j];
                a = fmaf(h0, W2[(k4 * 4 + 0) * 16 + j], a);
                a = fmaf(h1, W2[(k4 * 4 + 1) * 16 + j], a);
                a = fmaf(h2, W2[(k4 * 4 + 2) * 16 + j], a);
                a = fmaf(h3, W2[(k4 * 4 + 3) * 16 + j], a);
                acc[j] = a;
            }
        }
#pragma unroll
        for (int j = 0; j < 16; ++j)
            cacc[j] = fmaf(m, fmaxf(acc[j] + b2[j], 0.f), cacc[j]);
    }

    // reduce the 8 d-slots per (b,j): lanes L<->L^32 in-wave, then 4 waves via LDS
#pragma unroll
    for (int j = 0; j < 16; ++j) cacc[j] += __shfl_xor(cacc[j], 32);
    __shared__ float red[4][544];   // 32*17 padded
    const int wv   = t >> 6;
    const int lane = t & 63;
    if (lane < 32) {
#pragma unroll
        for (int j = 0; j < 16; ++j) red[wv][b * 17 + j] = cacc[j];
    }
    __syncthreads();
    for (int o = t; o < 512; o += 256) {
        const int ob = o >> 4, oj = o & 15;
        const int idx = ob * 17 + oj;
        atomicAdd(cws + o, red[0][idx] + red[1][idx] + red[2][idx] + red[3][idx]);
    }
}

// ---------------- C: c -> enc -> mu/logvar -> pz -> base_j   (single block)
__global__ __launch_bounds__(256) void kC(const float* __restrict__ cws,
                                          const float* __restrict__ We1,
                                          const float* __restrict__ be1,
                                          const float* __restrict__ We2,
                                          const float* __restrict__ be2,
                                          const float* __restrict__ Wz,
                                          const float* __restrict__ bz,
                                          const float* __restrict__ Wj1,
                                          const float* __restrict__ bj1,
                                          float* __restrict__ out,
                                          float* __restrict__ basews)
{
    const int t = threadIdx.x;
    __shared__ float sc[512];
    __shared__ float henc[32 * 256];
    __shared__ float encl[32 * 64];
    __shared__ float pzl[32 * 128];
    sc[t] = cws[t];
    sc[t + 256] = cws[t + 256];
    __syncthreads();
    // henc = relu(c @ We1 + be1)
    for (int idx = t; idx < 32 * 256; idx += 256) {
        const int bb = idx >> 8, e = idx & 255;
        float a = be1[e];
#pragma unroll
        for (int i = 0; i < 16; ++i) a = fmaf(sc[bb * 16 + i], We1[i * 256 + e], a);
        henc[idx] = fmaxf(a, 0.f);
    }
    __syncthreads();
    // enc = henc @ We2 + be2 ; write mu/logvar
    for (int idx = t; idx < 32 * 64; idx += 256) {
        const int bb = idx >> 6, o = idx & 63;
        float a = be2[o];
        for (int i = 0; i < 256; ++i) a = fmaf(henc[bb * 256 + i], We2[i * 64 + o], a);
        encl[idx] = a;
        if (o < 32) out[640000 + bb * 32 + o] = a;
        else        out[641024 + bb * 32 + (o - 32)] = a;
    }
    __syncthreads();
    // pz = relu(mu @ Wz + bz)
    for (int idx = t; idx < 32 * 128; idx += 256) {
        const int bb = idx >> 7, p = idx & 127;
        float a = bz[p];
#pragma unroll
        for (int i = 0; i < 32; ++i) a = fmaf(encl[bb * 64 + i], Wz[i * 128 + p], a);
        pzl[idx] = fmaxf(a, 0.f);
    }
    __syncthreads();
    // base_j = pz @ Wj1[:128] + bj1
    for (int idx = t; idx < 32 * 128; idx += 256) {
        const int bb = idx >> 7, k = idx & 127;
        float a = bj1[k];
        for (int i = 0; i < 128; ++i) a = fmaf(pzl[bb * 128 + i], Wj1[i * 128 + k], a);
        basews[idx] = a;
    }
}

// ---------------- D: rec[b][d] = sum_k relu(base[b][k] + FjT[k][d]) * Wj2[k] + bj2
__global__ __launch_bounds__(256) void kD(const float* __restrict__ FjT,
                                          const float* __restrict__ basews,
                                          const float* __restrict__ Wj2,
                                          const float* __restrict__ bj2,
                                          float* __restrict__ rec)
{
    const int d  = blockIdx.x * 256 + threadIdx.x;
    const int bq = blockIdx.y * 4;
    if (d >= Dn) return;
    const float* __restrict__ bA = basews + (bq + 0) * 128;
    const float* __restrict__ bB = basews + (bq + 1) * 128;
    const float* __restrict__ bC = basews + (bq + 2) * 128;
    const float* __restrict__ bD = basews + (bq + 3) * 128;
    float a0 = 0.f, a1 = 0.f, a2 = 0.f, a3 = 0.f;
#pragma unroll 8
    for (int k = 0; k < 128; ++k) {
        const float fj = FjT[k * Dn + d];
        const float w  = Wj2[k];
        a0 = fmaf(fmaxf(fj + bA[k], 0.f), w, a0);
        a1 = fmaf(fmaxf(fj + bB[k], 0.f), w, a1);
        a2 = fmaf(fmaxf(fj + bC[k], 0.f), w, a2);
        a3 = fmaf(fmaxf(fj + bD[k], 0.f), w, a3);
    }
    const float bj = bj2[0];
    rec[(bq + 0) * Dn + d] = a0 + bj;
    rec[(bq + 1) * Dn + d] = a1 + bj;
    rec[(bq + 2) * Dn + d] = a2 + bj;
    rec[(bq + 3) * Dn + d] = a3 + bj;
}

extern "C" void kernel_launch(void* const* d_in, const int* in_sizes, int n_in,
                              void* d_out, int out_size, void* d_ws, size_t ws_size,
                              hipStream_t stream)
{
    const float* x       = (const float*)d_in[0];
    const int*   mask    = (const int*)d_in[1];
    const float* F_embed = (const float*)d_in[2];
    const float* f_bias  = (const float*)d_in[3];
    const float* W1      = (const float*)d_in[4];
    const float* b1      = (const float*)d_in[5];
    const float* W2      = (const float*)d_in[6];
    const float* b2      = (const float*)d_in[7];
    const float* We1     = (const float*)d_in[8];
    const float* be1     = (const float*)d_in[9];
    const float* We2     = (const float*)d_in[10];
    const float* be2     = (const float*)d_in[11];
    const float* Wz      = (const float*)d_in[12];
    const float* bz      = (const float*)d_in[13];
    const float* Wj1     = (const float*)d_in[14];
    const float* bj1     = (const float*)d_in[15];
    const float* Wj2     = (const float*)d_in[16];
    const float* bj2     = (const float*)d_in[17];
    float* out = (float*)d_out;
    float* ws  = (float*)d_ws;

    float* F1     = ws;
    float* FjT    = ws + 2560000;
    float* cws    = ws + 5120000;
    float* basews = ws + 5120512;

    hipMemsetAsync(cws, 0, 512 * sizeof(float), stream);
    kA1<<<2500, 256, 0, stream>>>(F_embed, f_bias, W1, b1, F1);
    kA2<<<dim3(79, 16), 256, 0, stream>>>(F_embed, f_bias, Wj1, FjT);
    kB<<<500, 256, 0, stream>>>(x, mask, F1, W1, W2, b2, cws);
    kC<<<1, 256, 0, stream>>>(cws, We1, be1, We2, be2, Wz, bz, Wj1, bj1, out, basews);
    kD<<<dim3(79, 8), 256, 0, stream>>>(FjT, basews, Wj2, bj2, out);
}

// Round 4
// 189.858 us; speedup vs baseline: 1.2784x; 1.2784x over previous
//
#include <hip/hip_runtime.h>

#define Dn 20000
#define Bn 32

// ws layout (floats), total ~20.5 MB (same footprint as round-0, proven to fit):
//   F1      : [20000][128]  at 0
//   FjT     : [128][20000]  at 2,560,000   (overlaid with partial; kA2 runs AFTER kR)
//   partial : [2500][512]   at 2,560,000   (written by kB, consumed by kR, then clobbered by kA2)
//   cws     : [32][16]      at 5,120,000
//   base    : [32][128]     at 5,120,512

// ---------------- A1: F1[d][k] = b1[k] + f_bias[d]*W1[17][k] + sum_i F_embed[d][i]*W1[1+i][k]
__global__ __launch_bounds__(256) void kA1(const float* __restrict__ F_embed,
                                           const float* __restrict__ f_bias,
                                           const float* __restrict__ W1,
                                           const float* __restrict__ b1,
                                           float* __restrict__ F1)
{
    const int t  = threadIdx.x;
    const int k  = t & 127;
    const int dl = t >> 7;
    const int d0 = blockIdx.x * 8;
    float w[17];
#pragma unroll
    for (int i = 0; i < 16; ++i) w[i] = W1[(1 + i) * 128 + k];
    w[16] = W1[17 * 128 + k];
    const float bb = b1[k];
#pragma unroll
    for (int r = 0; r < 4; ++r) {
        const int d = d0 + r * 2 + dl;   // 2500*8 = 20000 exact
        float acc = fmaf(f_bias[d], w[16], bb);
#pragma unroll
        for (int i = 0; i < 16; ++i) acc = fmaf(F_embed[d * 16 + i], w[i], acc);
        F1[d * 128 + k] = acc;
    }
}

// ---------------- A2: FjT[k][d] = f_bias[d]*Wj1[144][k] + sum_i F_embed[d][i]*Wj1[128+i][k]
__global__ __launch_bounds__(256) void kA2(const float* __restrict__ F_embed,
                                           const float* __restrict__ f_bias,
                                           const float* __restrict__ Wj1,
                                           float* __restrict__ FjT)
{
    const int d  = blockIdx.x * 256 + threadIdx.x;
    const int kg = blockIdx.y * 8;
    if (d >= Dn) return;
    const float4* fe4 = (const float4*)(F_embed + d * 16);
    float fe[16];
    {
        float4 a = fe4[0], b = fe4[1], c = fe4[2], e = fe4[3];
        fe[0]=a.x; fe[1]=a.y; fe[2]=a.z; fe[3]=a.w;
        fe[4]=b.x; fe[5]=b.y; fe[6]=b.z; fe[7]=b.w;
        fe[8]=c.x; fe[9]=c.y; fe[10]=c.z; fe[11]=c.w;
        fe[12]=e.x; fe[13]=e.y; fe[14]=e.z; fe[15]=e.w;
    }
    const float fb = f_bias[d];
#pragma unroll
    for (int j = 0; j < 8; ++j) {
        const int k = kg + j;
        float acc = fb * Wj1[144 * 128 + k];
#pragma unroll
        for (int i = 0; i < 16; ++i) acc = fmaf(fe[i], Wj1[(128 + i) * 128 + k], acc);
        FjT[k * Dn + d] = acc;
    }
}

// ---------------- B: fused stage1+2 + masked partial reduce, 8 d per block, 2500 blocks
__global__ __launch_bounds__(256) void kB(const float* __restrict__ x,
                                          const int* __restrict__ mask,
                                          const float* __restrict__ F1,
                                          const float* __restrict__ W1,  // row 0 used
                                          const float* __restrict__ W2,
                                          const float* __restrict__ b2,
                                          float* __restrict__ partial)
{
    const int t   = threadIdx.x;
    const int b   = t & 31;
    const int dsl = t >> 5;
    const int d   = blockIdx.x * 8 + dsl;   // 2500*8 = 20000 exact

    const float xv = x[b * Dn + d];
    const float m  = (float)mask[b * Dn + d];

    float acc[16];
#pragma unroll
    for (int j = 0; j < 16; ++j) acc[j] = 0.f;

    const float4* f14 = (const float4*)(F1 + d * 128);
#pragma unroll 8
    for (int k4 = 0; k4 < 32; ++k4) {
        const float4 f = f14[k4];
        const float h0 = fmaxf(fmaf(xv, W1[k4 * 4 + 0], f.x), 0.f);
        const float h1 = fmaxf(fmaf(xv, W1[k4 * 4 + 1], f.y), 0.f);
        const float h2 = fmaxf(fmaf(xv, W1[k4 * 4 + 2], f.z), 0.f);
        const float h3 = fmaxf(fmaf(xv, W1[k4 * 4 + 3], f.w), 0.f);
#pragma unroll
        for (int j = 0; j < 16; ++j) {
            float a = acc[j];
            a = fmaf(h0, W2[(k4 * 4 + 0) * 16 + j], a);
            a = fmaf(h1, W2[(k4 * 4 + 1) * 16 + j], a);
            a = fmaf(h2, W2[(k4 * 4 + 2) * 16 + j], a);
            a = fmaf(h3, W2[(k4 * 4 + 3) * 16 + j], a);
            acc[j] = a;
        }
    }
#pragma unroll
    for (int j = 0; j < 16; ++j) acc[j] = m * fmaxf(acc[j] + b2[j], 0.f);

    // reduce over the 8 d-slots: lane L <-> L^32 in-wave, then 4 waves via LDS
#pragma unroll
    for (int j = 0; j < 16; ++j) acc[j] += __shfl_xor(acc[j], 32);
    __shared__ float red[4][544];   // 32*17 padded
    const int wv   = t >> 6;
    const int lane = t & 63;
    if (lane < 32) {
#pragma unroll
        for (int j = 0; j < 16; ++j) red[wv][b * 17 + j] = acc[j];
    }
    __syncthreads();
    float* __restrict__ po = partial + blockIdx.x * 512;
    for (int o = t; o < 512; o += 256) {
        const int ob = o >> 4, oj = o & 15;
        const int idx = ob * 17 + oj;
        po[o] = red[0][idx] + red[1][idx] + red[2][idx] + red[3][idx];
    }
}

// ---------------- R: cws[o] += sum over 2500 block-partials
__global__ __launch_bounds__(256) void kR(const float* __restrict__ partial,
                                          float* __restrict__ cws)
{
    const int o  = blockIdx.x * 256 + threadIdx.x;  // 2 x-blocks -> o in [0,512)
    const int r0 = blockIdx.y * 250;                // 10 y-blocks -> 2500 rows
    float s = 0.f;
#pragma unroll 5
    for (int r = 0; r < 250; ++r) s += partial[(r0 + r) * 512 + o];
    atomicAdd(cws + o, s);
}

// ---------------- C: per-b block: c -> henc -> enc(mu/logvar) -> pz -> base_j
__global__ __launch_bounds__(256) void kC(const float* __restrict__ cws,
                                          const float* __restrict__ We1,
                                          const float* __restrict__ be1,
                                          const float* __restrict__ We2,
                                          const float* __restrict__ be2,
                                          const float* __restrict__ Wz,
                                          const float* __restrict__ bz,
                                          const float* __restrict__ Wj1,
                                          const float* __restrict__ bj1,
                                          float* __restrict__ out,
                                          float* __restrict__ basews)
{
    const int b = blockIdx.x;
    const int t = threadIdx.x;
    __shared__ float cb[16];
    __shared__ float henc[256];
    __shared__ float ep[4][64];
    __shared__ float zl[32];
    __shared__ float pzl[128];
    __shared__ float jp[2][128];

    if (t < 16) cb[t] = cws[b * 16 + t];
    __syncthreads();

    // E1: henc[t] = relu(c @ We1 + be1)
    {
        float a = be1[t];
#pragma unroll
        for (int i = 0; i < 16; ++i) a = fmaf(cb[i], We1[i * 256 + t], a);
        henc[t] = fmaxf(a, 0.f);
    }
    __syncthreads();

    // E2: enc[o] = henc @ We2 + be2, split-K over 4 thread-groups
    {
        const int o = t & 63, s = t >> 6;
        float a = 0.f;
#pragma unroll 8
        for (int i = 0; i < 64; ++i) a = fmaf(henc[s * 64 + i], We2[(s * 64 + i) * 64 + o], a);
        ep[s][o] = a;
    }
    __syncthreads();
    if (t < 64) {
        const float e = be2[t] + ep[0][t] + ep[1][t] + ep[2][t] + ep[3][t];
        if (t < 32) { out[640000 + b * 32 + t] = e; zl[t] = e; }   // mu (= z)
        else        { out[641024 + b * 32 + (t - 32)] = e; }       // logvar
    }
    __syncthreads();

    // Z: pz[p] = relu(z @ Wz + bz)
    if (t < 128) {
        float a = bz[t];
#pragma unroll 8
        for (int i = 0; i < 32; ++i) a = fmaf(zl[i], Wz[i * 128 + t], a);
        pzl[t] = fmaxf(a, 0.f);
    }
    __syncthreads();

    // J: base[k] = pz @ Wj1[:128] + bj1, split-K over 2 thread-groups
    {
        const int k = t & 127, s = t >> 7;
        float a = 0.f;
#pragma unroll 8
        for (int i = 0; i < 64; ++i) a = fmaf(pzl[s * 64 + i], Wj1[(s * 64 + i) * 128 + k], a);
        jp[s][k] = a;
    }
    __syncthreads();
    if (t < 128) basews[b * 128 + t] = bj1[t] + jp[0][t] + jp[1][t];
}

// ---------------- D: rec[b][d] = sum_k relu(base[b][k] + FjT[k][d]) * Wj2[k] + bj2
__global__ __launch_bounds__(256) void kD(const float* __restrict__ FjT,
                                          const float* __restrict__ basews,
                                          const float* __restrict__ Wj2,
                                          const float* __restrict__ bj2,
                                          float* __restrict__ rec)
{
    const int d  = blockIdx.x * 256 + threadIdx.x;
    const int bq = blockIdx.y * 4;
    if (d >= Dn) return;
    const float* __restrict__ bA = basews + (bq + 0) * 128;
    const float* __restrict__ bB = basews + (bq + 1) * 128;
    const float* __restrict__ bC = basews + (bq + 2) * 128;
    const float* __restrict__ bD = basews + (bq + 3) * 128;
    float a0 = 0.f, a1 = 0.f, a2 = 0.f, a3 = 0.f;
#pragma unroll 8
    for (int k = 0; k < 128; ++k) {
        const float fj = FjT[k * Dn + d];
        const float w  = Wj2[k];
        a0 = fmaf(fmaxf(fj + bA[k], 0.f), w, a0);
        a1 = fmaf(fmaxf(fj + bB[k], 0.f), w, a1);
        a2 = fmaf(fmaxf(fj + bC[k], 0.f), w, a2);
        a3 = fmaf(fmaxf(fj + bD[k], 0.f), w, a3);
    }
    const float bj = bj2[0];
    rec[(bq + 0) * Dn + d] = a0 + bj;
    rec[(bq + 1) * Dn + d] = a1 + bj;
    rec[(bq + 2) * Dn + d] = a2 + bj;
    rec[(bq + 3) * Dn + d] = a3 + bj;
}

extern "C" void kernel_launch(void* const* d_in, const int* in_sizes, int n_in,
                              void* d_out, int out_size, void* d_ws, size_t ws_size,
                              hipStream_t stream)
{
    const float* x       = (const float*)d_in[0];
    const int*   mask    = (const int*)d_in[1];
    const float* F_embed = (const float*)d_in[2];
    const float* f_bias  = (const float*)d_in[3];
    const float* W1      = (const float*)d_in[4];
    const float* b1      = (const float*)d_in[5];
    const float* W2      = (const float*)d_in[6];
    const float* b2      = (const float*)d_in[7];
    const float* We1     = (const float*)d_in[8];
    const float* be1     = (const float*)d_in[9];
    const float* We2     = (const float*)d_in[10];
    const float* be2     = (const float*)d_in[11];
    const float* Wz      = (const float*)d_in[12];
    const float* bz      = (const float*)d_in[13];
    const float* Wj1     = (const float*)d_in[14];
    const float* bj1     = (const float*)d_in[15];
    const float* Wj2     = (const float*)d_in[16];
    const float* bj2     = (const float*)d_in[17];
    float* out = (float*)d_out;
    float* ws  = (float*)d_ws;

    float* F1      = ws;
    float* FjT     = ws + 2560000;
    float* partial = ws + 2560000;   // overlays FjT; consumed by kR before kA2 writes FjT
    float* cws     = ws + 5120000;
    float* basews  = ws + 5120512;

    hipMemsetAsync(cws, 0, 512 * sizeof(float), stream);
    kA1<<<2500, 256, 0, stream>>>(F_embed, f_bias, W1, b1, F1);
    kB<<<2500, 256, 0, stream>>>(x, mask, F1, W1, W2, b2, partial);
    kR<<<dim3(2, 10), 256, 0, stream>>>(partial, cws);
    kC<<<32, 256, 0, stream>>>(cws, We1, be1, We2, be2, Wz, bz, Wj1, bj1, out, basews);
    kA2<<<dim3(79, 16), 256, 0, stream>>>(F_embed, f_bias, Wj1, FjT);
    kD<<<dim3(79, 8), 256, 0, stream>>>(FjT, basews, Wj2, bj2, out);
}

// Round 5
// 159.439 us; speedup vs baseline: 1.5224x; 1.1908x over previous
//
#include <hip/hip_runtime.h>
#include <hip/hip_bf16.h>

#define Dn 20000
#define Bn 32

typedef short bf8_t __attribute__((ext_vector_type(8)));   // 8 bf16 in 4 VGPRs
typedef float f32x4 __attribute__((ext_vector_type(4)));

static __device__ __forceinline__ short f2bf(float f) {
    __hip_bfloat16 h = __float2bfloat16(f);
    return __builtin_bit_cast(short, h);
}

// ws layout (floats), total ~20.5 MB:
//   F1      : [20000][128]  at 0
//   FjT     : [128][20000]  at 2,560,000   (overlaid with partial; kA2 runs AFTER kR)
//   partial : [1250][512]   at 2,560,000
//   cws     : [32][16]      at 5,120,000
//   base    : [32][128]     at 5,120,512

// ---------------- A1: F1[d][k] = b1[k] + f_bias[d]*W1[17][k] + sum_i F_embed[d][i]*W1[1+i][k]
__global__ __launch_bounds__(256) void kA1(const float* __restrict__ F_embed,
                                           const float* __restrict__ f_bias,
                                           const float* __restrict__ W1,
                                           const float* __restrict__ b1,
                                           float* __restrict__ F1)
{
    const int t  = threadIdx.x;
    const int k  = t & 127;
    const int dl = t >> 7;
    const int d0 = blockIdx.x * 8;
    float w[17];
#pragma unroll
    for (int i = 0; i < 16; ++i) w[i] = W1[(1 + i) * 128 + k];
    w[16] = W1[17 * 128 + k];
    const float bb = b1[k];
#pragma unroll
    for (int r = 0; r < 4; ++r) {
        const int d = d0 + r * 2 + dl;   // 2500*8 = 20000 exact
        float acc = fmaf(f_bias[d], w[16], bb);
#pragma unroll
        for (int i = 0; i < 16; ++i) acc = fmaf(F_embed[d * 16 + i], w[i], acc);
        F1[d * 128 + k] = acc;
    }
}

// ---------------- A2: FjT[k][d] = f_bias[d]*Wj1[144][k] + sum_i F_embed[d][i]*Wj1[128+i][k]
__global__ __launch_bounds__(256) void kA2(const float* __restrict__ F_embed,
                                           const float* __restrict__ f_bias,
                                           const float* __restrict__ Wj1,
                                           float* __restrict__ FjT)
{
    const int d  = blockIdx.x * 256 + threadIdx.x;
    const int kg = blockIdx.y * 8;
    if (d >= Dn) return;
    const float4* fe4 = (const float4*)(F_embed + d * 16);
    float fe[16];
    {
        float4 a = fe4[0], b = fe4[1], c = fe4[2], e = fe4[3];
        fe[0]=a.x; fe[1]=a.y; fe[2]=a.z; fe[3]=a.w;
        fe[4]=b.x; fe[5]=b.y; fe[6]=b.z; fe[7]=b.w;
        fe[8]=c.x; fe[9]=c.y; fe[10]=c.z; fe[11]=c.w;
        fe[12]=e.x; fe[13]=e.y; fe[14]=e.z; fe[15]=e.w;
    }
    const float fb = f_bias[d];
#pragma unroll
    for (int j = 0; j < 8; ++j) {
        const int k = kg + j;
        float acc = fb * Wj1[144 * 128 + k];
#pragma unroll
        for (int i = 0; i < 16; ++i) acc = fmaf(fe[i], Wj1[(128 + i) * 128 + k], acc);
        FjT[k * Dn + d] = acc;
    }
}

// ---------------- B (MFMA): per 16-d chunk, C[b][j] via mfma_f32_16x16x32_bf16
// block = 4 waves: wave w -> bhalf = w&1, dsub = w>>1 (8 d each).
// A rows = 16 b of the half; per-d epilogue applies b2/relu/mask and accumulates.
__global__ __launch_bounds__(256) void kB(const float* __restrict__ x,
                                          const int* __restrict__ mask,
                                          const float* __restrict__ F1,
                                          const float* __restrict__ W1,  // row 0 used
                                          const float* __restrict__ W2,
                                          const float* __restrict__ b2,
                                          float* __restrict__ partial)
{
    const int t = threadIdx.x;
    const int w = t >> 6;
    const int l = t & 63;
    const int bhalf = w & 1;
    const int dsub  = w >> 1;
    const int d0 = blockIdx.x * 16;            // 1250*16 = 20000 exact

    __shared__ float xs[528];   // xs[dl*33 + b]
    __shared__ float ms[528];
    __shared__ float red[512];

    // per-lane frag constants (independent of LDS)
    const int ko = (l >> 4) * 8;               // k-octet base within a 32-k step
    float w1f[4][8];
#pragma unroll
    for (int s = 0; s < 4; ++s)
#pragma unroll
        for (int e = 0; e < 8; ++e) w1f[s][e] = W1[s * 32 + ko + e];
    bf8_t bfr[4];
#pragma unroll
    for (int s = 0; s < 4; ++s)
#pragma unroll
        for (int e = 0; e < 8; ++e) bfr[s][e] = f2bf(W2[(s * 32 + ko + e) * 16 + (l & 15)]);
    const float b2v = b2[l & 15];

    // stage x, mask: transposed [dl][b]
#pragma unroll
    for (int i = 0; i < 2; ++i) {
        const int idx = t + i * 256;
        const int dl = idx & 15, b = idx >> 4;
        xs[dl * 33 + b] = x[b * Dn + d0 + dl];
        ms[dl * 33 + b] = (float)mask[b * Dn + d0 + dl];
    }
    __syncthreads();

    f32x4 cacc = {0.f, 0.f, 0.f, 0.f};
    const float xoff = 0.f;
    (void)xoff;
    for (int i = 0; i < 8; ++i) {
        const int dl = dsub * 8 + i;
        const int d  = d0 + dl;
        const float xv = xs[dl * 33 + bhalf * 16 + (l & 15)];
        f32x4 acc = {0.f, 0.f, 0.f, 0.f};
        const float* __restrict__ f1p = F1 + (size_t)d * 128 + ko;
#pragma unroll
        for (int s = 0; s < 4; ++s) {
            const float4 fa = *(const float4*)(f1p + s * 32);
            const float4 fb = *(const float4*)(f1p + s * 32 + 4);
            bf8_t af;
            af[0] = f2bf(fmaxf(fmaf(xv, w1f[s][0], fa.x), 0.f));
            af[1] = f2bf(fmaxf(fmaf(xv, w1f[s][1], fa.y), 0.f));
            af[2] = f2bf(fmaxf(fmaf(xv, w1f[s][2], fa.z), 0.f));
            af[3] = f2bf(fmaxf(fmaf(xv, w1f[s][3], fa.w), 0.f));
            af[4] = f2bf(fmaxf(fmaf(xv, w1f[s][4], fb.x), 0.f));
            af[5] = f2bf(fmaxf(fmaf(xv, w1f[s][5], fb.y), 0.f));
            af[6] = f2bf(fmaxf(fmaf(xv, w1f[s][6], fb.z), 0.f));
            af[7] = f2bf(fmaxf(fmaf(xv, w1f[s][7], fb.w), 0.f));
            acc = __builtin_amdgcn_mfma_f32_16x16x32_bf16(af, bfr[s], acc, 0, 0, 0);
        }
        // epilogue: lane holds C[m=(l>>4)*4+r][n=l&15]; b = bhalf*16 + m
#pragma unroll
        for (int r = 0; r < 4; ++r) {
            const float mvr = ms[dl * 33 + bhalf * 16 + (l >> 4) * 4 + r];
            cacc[r] = fmaf(mvr, fmaxf(acc[r] + b2v, 0.f), cacc[r]);
        }
    }

    // combine dsub halves in LDS, write block partial
    const int base = bhalf * 256 + (l >> 4) * 64 + (l & 15);
    if (dsub == 0) {
        red[base]      = cacc[0];
        red[base + 16] = cacc[1];
        red[base + 32] = cacc[2];
        red[base + 48] = cacc[3];
    }
    __syncthreads();
    if (dsub == 1) {
        red[base]      += cacc[0];
        red[base + 16] += cacc[1];
        red[base + 32] += cacc[2];
        red[base + 48] += cacc[3];
    }
    __syncthreads();
    float* __restrict__ po = partial + blockIdx.x * 512;
    po[t]       = red[t];
    po[t + 256] = red[t + 256];
}

// ---------------- R: cws[o] += sum over 1250 block-partials
__global__ __launch_bounds__(256) void kR(const float* __restrict__ partial,
                                          float* __restrict__ cws)
{
    const int o  = blockIdx.x * 256 + threadIdx.x;  // 2 x-blocks -> o in [0,512)
    const int r0 = blockIdx.y * 125;                // 10 y-blocks -> 1250 rows
    float s = 0.f;
#pragma unroll 5
    for (int r = 0; r < 125; ++r) s += partial[(r0 + r) * 512 + o];
    atomicAdd(cws + o, s);
}

// ---------------- C: per-b block: c -> henc -> enc(mu/logvar) -> pz -> base_j
__global__ __launch_bounds__(256) void kC(const float* __restrict__ cws,
                                          const float* __restrict__ We1,
                                          const float* __restrict__ be1,
                                          const float* __restrict__ We2,
                                          const float* __restrict__ be2,
                                          const float* __restrict__ Wz,
                                          const float* __restrict__ bz,
                                          const float* __restrict__ Wj1,
                                          const float* __restrict__ bj1,
                                          float* __restrict__ out,
                                          float* __restrict__ basews)
{
    const int b = blockIdx.x;
    const int t = threadIdx.x;
    __shared__ float cb[16];
    __shared__ float henc[256];
    __shared__ float ep[4][64];
    __shared__ float zl[32];
    __shared__ float pzl[128];
    __shared__ float jp[2][128];

    if (t < 16) cb[t] = cws[b * 16 + t];
    __syncthreads();

    {
        float a = be1[t];
#pragma unroll
        for (int i = 0; i < 16; ++i) a = fmaf(cb[i], We1[i * 256 + t], a);
        henc[t] = fmaxf(a, 0.f);
    }
    __syncthreads();

    {
        const int o = t & 63, s = t >> 6;
        float a = 0.f;
#pragma unroll 8
        for (int i = 0; i < 64; ++i) a = fmaf(henc[s * 64 + i], We2[(s * 64 + i) * 64 + o], a);
        ep[s][o] = a;
    }
    __syncthreads();
    if (t < 64) {
        const float e = be2[t] + ep[0][t] + ep[1][t] + ep[2][t] + ep[3][t];
        if (t < 32) { out[640000 + b * 32 + t] = e; zl[t] = e; }
        else        { out[641024 + b * 32 + (t - 32)] = e; }
    }
    __syncthreads();

    if (t < 128) {
        float a = bz[t];
#pragma unroll 8
        for (int i = 0; i < 32; ++i) a = fmaf(zl[i], Wz[i * 128 + t], a);
        pzl[t] = fmaxf(a, 0.f);
    }
    __syncthreads();

    {
        const int k = t & 127, s = t >> 7;
        float a = 0.f;
#pragma unroll 8
        for (int i = 0; i < 64; ++i) a = fmaf(pzl[s * 64 + i], Wj1[(s * 64 + i) * 128 + k], a);
        jp[s][k] = a;
    }
    __syncthreads();
    if (t < 128) basews[b * 128 + t] = bj1[t] + jp[0][t] + jp[1][t];
}

// ---------------- D: rec[b][d] = sum_k relu(base[b][k] + FjT[k][d]) * Wj2[k] + bj2
__global__ __launch_bounds__(256) void kD(const float* __restrict__ FjT,
                                          const float* __restrict__ basews,
                                          const float* __restrict__ Wj2,
                                          const float* __restrict__ bj2,
                                          float* __restrict__ rec)
{
    const int d  = blockIdx.x * 256 + threadIdx.x;
    const int bq = blockIdx.y * 4;
    if (d >= Dn) return;
    const float* __restrict__ bA = basews + (bq + 0) * 128;
    const float* __restrict__ bB = basews + (bq + 1) * 128;
    const float* __restrict__ bC = basews + (bq + 2) * 128;
    const float* __restrict__ bD = basews + (bq + 3) * 128;
    float a0 = 0.f, a1 = 0.f, a2 = 0.f, a3 = 0.f;
#pragma unroll 8
    for (int k = 0; k < 128; ++k) {
        const float fj = FjT[k * Dn + d];
        const float w  = Wj2[k];
        a0 = fmaf(fmaxf(fj + bA[k], 0.f), w, a0);
        a1 = fmaf(fmaxf(fj + bB[k], 0.f), w, a1);
        a2 = fmaf(fmaxf(fj + bC[k], 0.f), w, a2);
        a3 = fmaf(fmaxf(fj + bD[k], 0.f), w, a3);
    }
    const float bj = bj2[0];
    rec[(bq + 0) * Dn + d] = a0 + bj;
    rec[(bq + 1) * Dn + d] = a1 + bj;
    rec[(bq + 2) * Dn + d] = a2 + bj;
    rec[(bq + 3) * Dn + d] = a3 + bj;
}

extern "C" void kernel_launch(void* const* d_in, const int* in_sizes, int n_in,
                              void* d_out, int out_size, void* d_ws, size_t ws_size,
                              hipStream_t stream)
{
    const float* x       = (const float*)d_in[0];
    const int*   mask    = (const int*)d_in[1];
    const float* F_embed = (const float*)d_in[2];
    const float* f_bias  = (const float*)d_in[3];
    const float* W1      = (const float*)d_in[4];
    const float* b1      = (const float*)d_in[5];
    const float* W2      = (const float*)d_in[6];
    const float* b2      = (const float*)d_in[7];
    const float* We1     = (const float*)d_in[8];
    const float* be1     = (const float*)d_in[9];
    const float* We2     = (const float*)d_in[10];
    const float* be2     = (const float*)d_in[11];
    const float* Wz      = (const float*)d_in[12];
    const float* bz      = (const float*)d_in[13];
    const float* Wj1     = (const float*)d_in[14];
    const float* bj1     = (const float*)d_in[15];
    const float* Wj2     = (const float*)d_in[16];
    const float* bj2     = (const float*)d_in[17];
    float* out = (float*)d_out;
    float* ws  = (float*)d_ws;

    float* F1      = ws;
    float* FjT     = ws + 2560000;
    float* partial = ws + 2560000;   // overlays FjT; consumed by kR before kA2 writes FjT
    float* cws     = ws + 5120000;
    float* basews  = ws + 5120512;

    hipMemsetAsync(cws, 0, 512 * sizeof(float), stream);
    kA1<<<2500, 256, 0, stream>>>(F_embed, f_bias, W1, b1, F1);
    kB<<<1250, 256, 0, stream>>>(x, mask, F1, W1, W2, b2, partial);
    kR<<<dim3(2, 10), 256, 0, stream>>>(partial, cws);
    kC<<<32, 256, 0, stream>>>(cws, We1, be1, We2, be2, Wz, bz, Wj1, bj1, out, basews);
    kA2<<<dim3(79, 16), 256, 0, stream>>>(F_embed, f_bias, Wj1, FjT);
    kD<<<dim3(79, 8), 256, 0, stream>>>(FjT, basews, Wj2, bj2, out);
}